// Round 1
// baseline (220.491 us; speedup 1.0000x reference)
//
#include <hip/hip_runtime.h>
#include <hip/hip_bf16.h>

#define B_DIM 8
#define C_DIM 256
#define S_DIM 2304

typedef __attribute__((ext_vector_type(8))) short short8;
typedef __attribute__((ext_vector_type(4))) float floatx4;

// Async global->LDS, 16B per lane. LDS dest is wave-uniform base + lane*16.
__device__ __forceinline__ void gload_lds16(const __hip_bfloat16* g, __hip_bfloat16* l) {
    __builtin_amdgcn_global_load_lds(
        (__attribute__((address_space(1))) void*)(void*)(g),
        (__attribute__((address_space(3))) void*)(l), 16, 0, 0);
}

// ---------------------------------------------------------------------------
// Kernel 1: per-(b,s) L2-normalize over C and transpose [B,C,S] f32 ->
// [B,S,C] bf16.  Block = 256 threads handles 64 s-columns x 256 channels.
// Reads coalesced along S; writes coalesced along C via LDS transpose.
// ---------------------------------------------------------------------------
__global__ __launch_bounds__(256) void norm_transpose_kernel(
    const float* __restrict__ src, const float* __restrict__ dst,
    __hip_bfloat16* __restrict__ srcT, __hip_bfloat16* __restrict__ dstT) {
    const int s0 = blockIdx.x * 64;
    const int b  = blockIdx.y;
    const float* in = (blockIdx.z == 0 ? src : dst) + (size_t)b * C_DIM * S_DIM;
    __hip_bfloat16* out = (blockIdx.z == 0 ? srcT : dstT) + (size_t)b * S_DIM * C_DIM;

    // +8 pad keeps rows 16B-aligned (264*2 = 528 = 33*16) for b128 reads.
    __shared__ __align__(16) __hip_bfloat16 tile[64][C_DIM + 8];
    __shared__ float red[4][64];
    __shared__ float invn[64];

    const int t  = threadIdx.x;
    const int l  = t & 63;   // s-lane
    const int wv = t >> 6;   // wave id 0..3

    float ss = 0.f;
#pragma unroll 8
    for (int c = wv; c < C_DIM; c += 4) {
        float v = in[(size_t)c * S_DIM + s0 + l];   // 64 lanes coalesced along s
        ss += v * v;
        tile[l][c] = __float2bfloat16(v);
    }
    red[wv][l] = ss;
    __syncthreads();
    if (t < 64) invn[t] = rsqrtf(red[0][t] + red[1][t] + red[2][t] + red[3][t]);
    __syncthreads();

    // Write [s][c], 8 bf16 (16B) per thread, consecutive threads -> consecutive c.
#pragma unroll
    for (int it = 0; it < 8; ++it) {
        int idx  = it * 256 + t;        // 0..2047
        int srow = idx >> 5;
        int c0   = (idx & 31) << 3;
        float inv = invn[srow];
        union { short8 v; __hip_bfloat16 h[8]; } u, o;
        u.v = *(const short8*)&tile[srow][c0];
#pragma unroll
        for (int j = 0; j < 8; ++j)
            o.h[j] = __float2bfloat16(__bfloat162float(u.h[j]) * inv);
        *(short8*)&out[(size_t)(s0 + srow) * C_DIM + c0] = o.v;
    }
}

// ---------------------------------------------------------------------------
// Kernel 2: per-batch GEMM  out[b][m][n] = relu( sum_k At[b][m][k]*Bt[b][n][k] )
// At,Bt: [B, S, C] bf16 (K-contiguous).  128x128 tile, BK=32, 4 waves,
// 4x4 mfma_f32_16x16x32_bf16 per wave, global_load_lds(16B) staging.
// ---------------------------------------------------------------------------
__global__ __launch_bounds__(256) void gemm_relu_kernel(
    const __hip_bfloat16* __restrict__ At, const __hip_bfloat16* __restrict__ Bt,
    float* __restrict__ out) {
    const int b  = blockIdx.z;
    const int m0 = blockIdx.y * 128;
    const int n0 = blockIdx.x * 128;
    const __hip_bfloat16* A  = At + (size_t)b * S_DIM * C_DIM;
    const __hip_bfloat16* Bp = Bt + (size_t)b * S_DIM * C_DIM;

    __shared__ __align__(16) __hip_bfloat16 As[128 * 32];
    __shared__ __align__(16) __hip_bfloat16 Bs[128 * 32];

    const int t    = threadIdx.x;
    const int lane = t & 63;
    const int wv   = t >> 6;

    const int fm = lane & 15;          // m (or n) within 16x16 fragment
    const int kq = (lane >> 4) << 3;   // k offset 0/8/16/24
    const int wr = (wv >> 1) << 6;     // wave row origin (0 or 64)
    const int wc = (wv & 1) << 6;      // wave col origin (0 or 64)

    // Staging: tile is 128 rows x 32 k = 8192 B = 8 chunks of 1024 B (64 lanes x 16B).
    // Wave wv owns chunks {2wv, 2wv+1}.  Element idx e = ch*512 + lane*8.
    const int ch0 = wv * 2;

    floatx4 acc[4][4] = {};

    for (int k0 = 0; k0 < C_DIM; k0 += 32) {
#pragma unroll
        for (int ci = 0; ci < 2; ++ci) {
            int ch  = ch0 + ci;
            int e   = ch * 512 + lane * 8;
            int row = e >> 5;
            int kc  = e & 31;
            gload_lds16(A  + (size_t)(m0 + row) * C_DIM + (k0 + kc), &As[ch * 512]);
            gload_lds16(Bp + (size_t)(n0 + row) * C_DIM + (k0 + kc), &Bs[ch * 512]);
        }
        __syncthreads();   // drains vmcnt -> staged data visible

        short8 af[4], bf[4];
#pragma unroll
        for (int i = 0; i < 4; ++i) {
            af[i] = *(const short8*)&As[(wr + i * 16 + fm) * 32 + kq];
            bf[i] = *(const short8*)&Bs[(wc + i * 16 + fm) * 32 + kq];
        }
#pragma unroll
        for (int i = 0; i < 4; ++i)
#pragma unroll
            for (int j = 0; j < 4; ++j)
                acc[i][j] = __builtin_amdgcn_mfma_f32_16x16x32_bf16(af[i], bf[j], acc[i][j], 0, 0, 0);
        __syncthreads();   // all reads done before next-iter overwrite
    }

    // Epilogue: C/D layout col = lane&15 (n), row = (lane>>4)*4 + reg (m). ReLU fused.
    float* Cp = out + (size_t)b * S_DIM * S_DIM;
    const int rq = (lane >> 4) << 2;
#pragma unroll
    for (int i = 0; i < 4; ++i) {
        int rbase = m0 + wr + i * 16 + rq;
#pragma unroll
        for (int j = 0; j < 4; ++j) {
            int col = n0 + wc + j * 16 + fm;
#pragma unroll
            for (int r = 0; r < 4; ++r)
                Cp[(size_t)(rbase + r) * S_DIM + col] = fmaxf(acc[i][j][r], 0.f);
        }
    }
}

extern "C" void kernel_launch(void* const* d_in, const int* in_sizes, int n_in,
                              void* d_out, int out_size, void* d_ws, size_t ws_size,
                              hipStream_t stream) {
    const float* src = (const float*)d_in[0];
    const float* dst = (const float*)d_in[1];
    float* out = (float*)d_out;

    // Workspace: srcT + dstT, each B*S*C bf16 = 9.44 MB (total 18.9 MB).
    __hip_bfloat16* srcT = (__hip_bfloat16*)d_ws;
    __hip_bfloat16* dstT = srcT + (size_t)B_DIM * S_DIM * C_DIM;

    dim3 g1(S_DIM / 64, B_DIM, 2);
    norm_transpose_kernel<<<g1, 256, 0, stream>>>(src, dst, srcT, dstT);

    dim3 g2(S_DIM / 128, S_DIM / 128, B_DIM);
    gemm_relu_kernel<<<g2, 256, 0, stream>>>(srcT, dstT, out);
}